// Round 1
// baseline (693.947 us; speedup 1.0000x reference)
//
#include <hip/hip_runtime.h>
#include <math.h>

#define BB 4
#define NN 16384
#define CC 384
#define NE 128
#define KK 64

// ---------------- K1: per-row sumsq + class-token dot ----------------
// scores[row] = dot(ct, x) * inv_norm(x)   (ranking-equivalent to reference)
// invn[row]   = 1 / max(||x||, 1e-12)
__global__ __launch_bounds__(256) void k_scores(const float* __restrict__ nf,
                                                const float* __restrict__ ct,
                                                float* __restrict__ scores,
                                                float* __restrict__ invn) {
    int wave = threadIdx.x >> 6;
    int lane = threadIdx.x & 63;
    int row  = blockIdx.x * 4 + wave;          // [0, B*N)
    const float* x = nf + (size_t)row * CC;
    float ss = 0.f, dt = 0.f;
#pragma unroll
    for (int k = 0; k < 6; ++k) {
        int c = lane + 64 * k;
        float v = x[c];
        ss += v * v;
        dt += ct[c] * v;
    }
#pragma unroll
    for (int off = 32; off; off >>= 1) {
        ss += __shfl_xor(ss, off, 64);
        dt += __shfl_xor(dt, off, 64);
    }
    if (lane == 0) {
        float inv = 1.0f / fmaxf(sqrtf(ss), 1e-12f);
        invn[row]   = inv;
        scores[row] = dt * inv;
    }
}

// ---------------- K2: top-128 centers per batch (order matters) ----------------
// 1024 threads, 16 register-resident values each; iterative block argmax with
// jax.lax.top_k tie semantics (equal value -> smaller index first).
__global__ __launch_bounds__(1024) void k_top128(const float* __restrict__ scores,
                                                 int* __restrict__ cidx) {
    __shared__ float cv[1024];
    __shared__ int   ci[1024];
    __shared__ int   win_i;
    int b = blockIdx.x;
    int t = threadIdx.x;
    const float* s = scores + b * NN;
    float v[16];
    float lmax = -INFINITY; int lidx = 0;
#pragma unroll
    for (int j = 0; j < 16; ++j) {
        v[j] = s[t + 1024 * j];
        if (v[j] > lmax) { lmax = v[j]; lidx = t + 1024 * j; }  // ascending n: > keeps smallest idx
    }
    for (int e = 0; e < NE; ++e) {
        cv[t] = lmax; ci[t] = lidx;
        __syncthreads();
        if (t < 64) {
            float bv = cv[t]; int bi = ci[t];
#pragma unroll
            for (int j = 1; j < 16; ++j) {
                float vv = cv[t + 64 * j]; int ii = ci[t + 64 * j];
                if (vv > bv || (vv == bv && ii < bi)) { bv = vv; bi = ii; }
            }
#pragma unroll
            for (int off = 32; off; off >>= 1) {
                float vv = __shfl_xor(bv, off, 64);
                int   ii = __shfl_xor(bi, off, 64);
                if (vv > bv || (vv == bv && ii < bi)) { bv = vv; bi = ii; }
            }
            if (t == 0) { win_i = bi; cidx[b * NE + e] = bi; }
        }
        __syncthreads();
        int w = win_i;
        if ((w & 1023) == t) {          // owner: mark extracted, rescan registers
            int jw = w >> 10;
            lmax = -INFINITY; lidx = 0;
#pragma unroll
            for (int j = 0; j < 16; ++j) {
                if (j == jw) v[j] = -INFINITY;
                if (v[j] > lmax) { lmax = v[j]; lidx = t + 1024 * j; }
            }
        }
        __syncthreads();
    }
}

// ---------------- K2b: gather normalized centers + spatial meta ----------------
__global__ __launch_bounds__(128) void k_centers(const float* __restrict__ nf,
                                                 const float* __restrict__ invn,
                                                 const int* __restrict__ cidx,
                                                 float* __restrict__ centers_n,
                                                 float* __restrict__ meta) {
    int be = blockIdx.x;             // b*NE + e
    int b  = be >> 7;
    int ci = cidx[be];
    float inv = invn[b * NN + ci];
    const float* src = nf + ((size_t)b * NN + ci) * CC;
    float* dst = centers_n + (size_t)be * CC;
    for (int c = threadIdx.x; c < CC; c += 128) dst[c] = src[c] * inv;
    if (threadIdx.x == 0) {
        float zc = (float)(ci >> 10) * 2.0f;
        float yc = (float)((ci >> 5) & 31);
        float xc = (float)(ci & 31);
        // max distance over separable grid = corner; exact integer arithmetic in fp32
        float mz = fmaxf(zc * zc, (30.f - zc) * (30.f - zc));
        float my = fmaxf(yc * yc, (31.f - yc) * (31.f - yc));
        float mx = fmaxf(xc * xc, (31.f - xc) * (31.f - xc));
        float md = sqrtf(mz + my + mx);
        meta[be * 4 + 0] = zc;
        meta[be * 4 + 1] = yc;
        meta[be * 4 + 2] = xc;
        meta[be * 4 + 3] = 1.0f / (md + 1e-8f);
    }
}

// ---------------- K3: fp32 GEMM (Ne x N) with fused spatial epilogue ----------------
// combined(b,e,n) = 0.9/temp * invn[n] * dot(centers_n[e], nf[n]) + 0.1*(1 - dist*inv_maxd)
// Tile: 128 edges x 64 nodes, K-chunk 32.  LDS k-major for ds_read_b128.
#define KT 32
__global__ __launch_bounds__(256) void k_gemm(const float* __restrict__ nf,
                                              const float* __restrict__ centers_n,
                                              const float* __restrict__ invn,
                                              const float* __restrict__ meta,
                                              const float* __restrict__ temp,
                                              float* __restrict__ outc) {
    __shared__ float As[KT][132];   // [k][e]  (128 + pad)
    __shared__ float Bs[KT][68];    // [k][n]  (64 + pad)
    __shared__ float ms[NE * 4];
    int b  = blockIdx.y;
    int n0 = blockIdx.x * 64;
    int t  = threadIdx.x;
    for (int i = t; i < NE * 4; i += 256) ms[i] = meta[b * NE * 4 + i];
    float acc[8][4];
#pragma unroll
    for (int i = 0; i < 8; ++i)
#pragma unroll
        for (int j = 0; j < 4; ++j) acc[i][j] = 0.f;
    int te = t >> 4, tn = t & 15;
    const float* Ab = centers_n + (size_t)b * NE * CC;
    const float* Bb = nf + ((size_t)b * NN + n0) * CC;
    for (int kt = 0; kt < CC; kt += KT) {
        __syncthreads();
#pragma unroll
        for (int i = 0; i < 16; ++i) {           // A: 128x32 = 4096 elems
            int idx = t + 256 * i;
            int e = idx >> 5, k = idx & 31;
            As[k][e] = Ab[e * CC + kt + k];
        }
#pragma unroll
        for (int i = 0; i < 8; ++i) {            // B: 64x32 = 2048 elems
            int idx = t + 256 * i;
            int r = idx >> 5, k = idx & 31;
            Bs[k][r] = Bb[(size_t)r * CC + kt + k];
        }
        __syncthreads();
#pragma unroll
        for (int k = 0; k < KT; ++k) {
            float a0[8], b0[4];
#pragma unroll
            for (int i = 0; i < 8; ++i) a0[i] = As[k][te * 8 + i];
#pragma unroll
            for (int j = 0; j < 4; ++j) b0[j] = Bs[k][tn * 4 + j];
#pragma unroll
            for (int i = 0; i < 8; ++i)
#pragma unroll
                for (int j = 0; j < 4; ++j) acc[i][j] += a0[i] * b0[j];
        }
    }
    float scale = 0.9f / temp[0];
    float invs[4], zf[4], yf[4], xf[4];
#pragma unroll
    for (int j = 0; j < 4; ++j) {
        int n = n0 + tn * 4 + j;
        invs[j] = invn[b * NN + n];
        zf[j] = (float)(n >> 10) * 2.0f;
        yf[j] = (float)((n >> 5) & 31);
        xf[j] = (float)(n & 31);
    }
#pragma unroll
    for (int i = 0; i < 8; ++i) {
        int e = te * 8 + i;
        float zc = ms[e * 4 + 0], yc = ms[e * 4 + 1], xc = ms[e * 4 + 2], invd = ms[e * 4 + 3];
        float vv[4];
#pragma unroll
        for (int j = 0; j < 4; ++j) {
            float dz = zf[j] - zc, dy = yf[j] - yc, dx = xf[j] - xc;
            float dist = sqrtf(dz * dz + dy * dy + dx * dx);
            vv[j] = scale * invs[j] * acc[i][j] + 0.1f * (1.0f - dist * invd);
        }
        float4* op = (float4*)(outc + ((size_t)(b * NE + e) * NN + n0 + tn * 4));
        *op = make_float4(vv[0], vv[1], vv[2], vv[3]);
    }
}

// ---------------- K4: top-64 per hyperedge (set only; order irrelevant) ----------------
__global__ __launch_bounds__(256) void k_top64(const float* __restrict__ comb,
                                               int* __restrict__ sel) {
    __shared__ float cv[256];
    __shared__ int   ci[256];
    __shared__ int   win_i;
    int be = blockIdx.x;
    int t  = threadIdx.x;
    const float* row = comb + (size_t)be * NN;
    float v[64];
    float lmax = -INFINITY; int lidx = 0;
#pragma unroll
    for (int j = 0; j < 64; ++j) {
        v[j] = row[t + 256 * j];
        if (v[j] > lmax) { lmax = v[j]; lidx = t + 256 * j; }
    }
    for (int s = 0; s < KK; ++s) {
        cv[t] = lmax; ci[t] = lidx;
        __syncthreads();
        if (t < 64) {
            float bv = cv[t]; int bi = ci[t];
#pragma unroll
            for (int j = 1; j < 4; ++j) {
                float vv = cv[t + 64 * j]; int ii = ci[t + 64 * j];
                if (vv > bv || (vv == bv && ii < bi)) { bv = vv; bi = ii; }
            }
#pragma unroll
            for (int off = 32; off; off >>= 1) {
                float vv = __shfl_xor(bv, off, 64);
                int   ii = __shfl_xor(bi, off, 64);
                if (vv > bv || (vv == bv && ii < bi)) { bv = vv; bi = ii; }
            }
            if (t == 0) { win_i = bi; sel[be * KK + s] = bi; }
        }
        __syncthreads();
        int w = win_i;
        if ((w & 255) == t) {
            int jw = w >> 8;
            lmax = -INFINITY; lidx = 0;
#pragma unroll
            for (int j = 0; j < 64; ++j) {
                if (j == jw) v[j] = -INFINITY;
                if (v[j] > lmax) { lmax = v[j]; lidx = t + 256 * j; }
            }
        }
        __syncthreads();
    }
}

// ---------------- K5: scatter ones into H (B, N, Ne) ----------------
__global__ __launch_bounds__(256) void k_scatter(const int* __restrict__ sel,
                                                 float* __restrict__ H) {
    int gid = blockIdx.x * 256 + threadIdx.x;   // [0, B*NE*KK)
    int b = gid >> 13;                          // NE*KK = 8192
    int e = (gid >> 6) & 127;
    int n = sel[gid];
    H[((size_t)b * NN + n) * NE + e] = 1.0f;
}

extern "C" void kernel_launch(void* const* d_in, const int* in_sizes, int n_in,
                              void* d_out, int out_size, void* d_ws, size_t ws_size,
                              hipStream_t stream) {
    const float* nf   = (const float*)d_in[0];   // (B, N, C) f32
    const float* ct   = (const float*)d_in[1];   // (1, 1, C) f32
    const float* temp = (const float*)d_in[2];   // (1,) f32
    float* out = (float*)d_out;                  // (B, N, Ne) f32 — also used as (B,Ne,N) scratch

    float* scores    = (float*)d_ws;                       // B*N
    float* invn      = scores + BB * NN;                   // B*N
    int*   cidx      = (int*)(invn + BB * NN);             // B*NE
    float* meta      = (float*)(cidx + BB * NE);           // B*NE*4
    float* centers_n = meta + BB * NE * 4;                 // B*NE*C
    int*   sel       = (int*)(centers_n + BB * NE * CC);   // B*NE*KK

    k_scores <<<BB * NN / 4, 256, 0, stream>>>(nf, ct, scores, invn);
    k_top128 <<<BB, 1024, 0, stream>>>(scores, cidx);
    k_centers<<<BB * NE, 128, 0, stream>>>(nf, invn, cidx, centers_n, meta);
    k_gemm   <<<dim3(NN / 64, BB), 256, 0, stream>>>(nf, centers_n, invn, meta, temp, out);
    k_top64  <<<BB * NE, 256, 0, stream>>>(out, sel);
    hipMemsetAsync(d_out, 0, (size_t)BB * NN * NE * sizeof(float), stream);
    k_scatter<<<BB * NE * KK / 256, 256, 0, stream>>>(sel, out);
}

// Round 2
// 414.184 us; speedup vs baseline: 1.6755x; 1.6755x over previous
//
#include <hip/hip_runtime.h>
#include <math.h>

#define BB 4
#define NN 16384
#define CC 384
#define NE 128
#define KK 64
#define EQCAP 256

// Monotone map: larger float -> larger u32 (total order, sign handled)
__device__ inline unsigned fkey(float f) {
    unsigned b = __float_as_uint(f);
    return (b & 0x80000000u) ? ~b : (b | 0x80000000u);
}

// ---------------- K1: per-row sumsq + class-token dot -> u32 ranking key ----------------
// key[row] = fkey(dot(ct,x) * inv_norm(x))   (ranking-equivalent to reference scores)
__global__ __launch_bounds__(256) void k_scores(const float* __restrict__ nf,
                                                const float* __restrict__ ct,
                                                unsigned* __restrict__ keys,
                                                float* __restrict__ invn) {
    int wave = threadIdx.x >> 6;
    int lane = threadIdx.x & 63;
    int row  = blockIdx.x * 4 + wave;          // [0, B*N)
    const float* x = nf + (size_t)row * CC;
    float4 a  = ((const float4*)x)[lane];          // elems 4*lane .. 4*lane+3   (0..255)
    float2 c2 = ((const float2*)(x + 256))[lane];  // elems 256+2*lane, +1       (256..383)
    float4 ta = ((const float4*)ct)[lane];
    float2 tc = ((const float2*)(ct + 256))[lane];
    float ss = a.x*a.x + a.y*a.y + a.z*a.z + a.w*a.w + c2.x*c2.x + c2.y*c2.y;
    float dt = ta.x*a.x + ta.y*a.y + ta.z*a.z + ta.w*a.w + tc.x*c2.x + tc.y*c2.y;
#pragma unroll
    for (int off = 32; off; off >>= 1) {
        ss += __shfl_xor(ss, off, 64);
        dt += __shfl_xor(dt, off, 64);
    }
    if (lane == 0) {
        float inv = 1.0f / fmaxf(sqrtf(ss), 1e-12f);
        invn[row] = inv;
        keys[row] = fkey(dt * inv);
    }
}

// ---------------- K2: top-128 centers per batch via radix select (order matters) ----------------
__global__ __launch_bounds__(1024) void k_top128(const unsigned* __restrict__ keys,
                                                 int* __restrict__ cidx) {
    __shared__ unsigned hist[256];
    __shared__ unsigned sh_prefix;
    __shared__ int sh_r;
    __shared__ unsigned cu[NE];
    __shared__ int cil[NE];
    __shared__ int eqi[EQCAP];
    __shared__ int cnt_gt, cnt_eq;
    int b = blockIdx.x;
    int t = threadIdx.x;
    const unsigned* k = keys + b * NN;
    if (t == 0) { sh_prefix = 0u; sh_r = NE; cnt_gt = 0; cnt_eq = 0; }
#pragma unroll
    for (int pass = 0; pass < 4; ++pass) {
        int shift = 24 - 8 * pass;
        unsigned hm = (pass == 0) ? 0u : (0xFFFFFFFFu << (shift + 8));
        if (t < 256) hist[t] = 0;
        __syncthreads();
        unsigned pf = sh_prefix;
        for (int n = t; n < NN; n += 1024) {
            unsigned u = k[n];
            if ((u & hm) == (pf & hm)) atomicAdd(&hist[(u >> shift) & 255], 1u);
        }
        __syncthreads();
        if (t == 0) {
            unsigned cum = 0, r = (unsigned)sh_r;
            for (int bin = 255; bin >= 0; --bin) {
                unsigned c = hist[bin];
                if (cum + c >= r) { sh_prefix |= (unsigned)bin << shift; sh_r = (int)(r - cum); break; }
                cum += c;
            }
        }
        __syncthreads();
    }
    unsigned T = sh_prefix;
    int r = sh_r;                       // # of ==T elements to include (smallest indices)
    for (int n = t; n < NN; n += 1024) {
        unsigned u = k[n];
        if (u > T) {
            int p = atomicAdd(&cnt_gt, 1);
            cu[p] = u; cil[p] = n;
        } else if (u == T) {
            int p = atomicAdd(&cnt_eq, 1);
            if (p < EQCAP) eqi[p] = n;
        }
    }
    __syncthreads();
    int ne = cnt_eq < EQCAP ? cnt_eq : EQCAP;
    if (t < ne) {
        int mine = eqi[t], rk = 0;
        for (int j = 0; j < ne; ++j) rk += (eqi[j] < mine);
        if (rk < r) { int p = cnt_gt + rk; cu[p] = T; cil[p] = mine; }
    }
    __syncthreads();
    if (t < NE) {
        unsigned mu = cu[t]; int mi = cil[t], rk = 0;
#pragma unroll 4
        for (int j = 0; j < NE; ++j) {
            unsigned ou = cu[j]; int oi = cil[j];
            rk += (ou > mu) || (ou == mu && oi < mi);
        }
        cidx[b * NE + rk] = mi;
    }
}

// ---------------- K2b: gather normalized centers + spatial meta ----------------
__global__ __launch_bounds__(128) void k_centers(const float* __restrict__ nf,
                                                 const float* __restrict__ invn,
                                                 const int* __restrict__ cidx,
                                                 float* __restrict__ centers_n,
                                                 float* __restrict__ meta) {
    int be = blockIdx.x;             // b*NE + e
    int b  = be >> 7;
    int ci = cidx[be];
    float inv = invn[b * NN + ci];
    const float* src = nf + ((size_t)b * NN + ci) * CC;
    float* dst = centers_n + (size_t)be * CC;
    for (int c = threadIdx.x; c < CC; c += 128) dst[c] = src[c] * inv;
    if (threadIdx.x == 0) {
        float zc = (float)(ci >> 10) * 2.0f;
        float yc = (float)((ci >> 5) & 31);
        float xc = (float)(ci & 31);
        float mz = fmaxf(zc * zc, (30.f - zc) * (30.f - zc));
        float my = fmaxf(yc * yc, (31.f - yc) * (31.f - yc));
        float mx = fmaxf(xc * xc, (31.f - xc) * (31.f - xc));
        float md = sqrtf(mz + my + mx);
        meta[be * 4 + 0] = zc;
        meta[be * 4 + 1] = yc;
        meta[be * 4 + 2] = xc;
        meta[be * 4 + 3] = 1.0f / (md + 1e-8f);
    }
}

// ---------------- K3: fp32 GEMM (Ne x N) with fused spatial epilogue -> u32 keys ----------------
#define KT 32
__global__ __launch_bounds__(256) void k_gemm(const float* __restrict__ nf,
                                              const float* __restrict__ centers_n,
                                              const float* __restrict__ invn,
                                              const float* __restrict__ meta,
                                              const float* __restrict__ temp,
                                              unsigned* __restrict__ outk) {
    __shared__ float As[KT][132];   // [k][e]
    __shared__ float Bs[KT][68];    // [k][n]
    __shared__ float ms[NE * 4];
    int b  = blockIdx.y;
    int n0 = blockIdx.x * 64;
    int t  = threadIdx.x;
    for (int i = t; i < NE * 4; i += 256) ms[i] = meta[b * NE * 4 + i];
    float acc[8][4];
#pragma unroll
    for (int i = 0; i < 8; ++i)
#pragma unroll
        for (int j = 0; j < 4; ++j) acc[i][j] = 0.f;
    int te = t >> 4, tn = t & 15;
    const float* Ab = centers_n + (size_t)b * NE * CC;
    const float* Bb = nf + ((size_t)b * NN + n0) * CC;
    for (int kt = 0; kt < CC; kt += KT) {
        __syncthreads();
#pragma unroll
        for (int i = 0; i < 16; ++i) {
            int idx = t + 256 * i;
            int e = idx >> 5, k = idx & 31;
            As[k][e] = Ab[e * CC + kt + k];
        }
#pragma unroll
        for (int i = 0; i < 8; ++i) {
            int idx = t + 256 * i;
            int r = idx >> 5, k = idx & 31;
            Bs[k][r] = Bb[(size_t)r * CC + kt + k];
        }
        __syncthreads();
#pragma unroll
        for (int k = 0; k < KT; ++k) {
            float a0[8], b0[4];
#pragma unroll
            for (int i = 0; i < 8; ++i) a0[i] = As[k][te * 8 + i];
#pragma unroll
            for (int j = 0; j < 4; ++j) b0[j] = Bs[k][tn * 4 + j];
#pragma unroll
            for (int i = 0; i < 8; ++i)
#pragma unroll
                for (int j = 0; j < 4; ++j) acc[i][j] += a0[i] * b0[j];
        }
    }
    float scale = 0.9f / temp[0];
    float invs[4], zf[4], yf[4], xf[4];
#pragma unroll
    for (int j = 0; j < 4; ++j) {
        int n = n0 + tn * 4 + j;
        invs[j] = invn[b * NN + n];
        zf[j] = (float)(n >> 10) * 2.0f;
        yf[j] = (float)((n >> 5) & 31);
        xf[j] = (float)(n & 31);
    }
#pragma unroll
    for (int i = 0; i < 8; ++i) {
        int e = te * 8 + i;
        float zc = ms[e * 4 + 0], yc = ms[e * 4 + 1], xc = ms[e * 4 + 2], invd = ms[e * 4 + 3];
        unsigned kk[4];
#pragma unroll
        for (int j = 0; j < 4; ++j) {
            float dz = zf[j] - zc, dy = yf[j] - yc, dx = xf[j] - xc;
            float dist = sqrtf(dz * dz + dy * dy + dx * dx);
            kk[j] = fkey(scale * invs[j] * acc[i][j] + 0.1f * (1.0f - dist * invd));
        }
        uint4* op = (uint4*)(outk + ((size_t)(b * NE + e) * NN + n0 + tn * 4));
        *op = make_uint4(kk[0], kk[1], kk[2], kk[3]);
    }
}

// ---------------- K4: top-64 per hyperedge via radix select (set only) ----------------
__global__ __launch_bounds__(256) void k_top64(const unsigned* __restrict__ comb,
                                               int* __restrict__ sel) {
    __shared__ unsigned hist[256];
    __shared__ unsigned sh_prefix;
    __shared__ int sh_r;
    __shared__ int eqi[EQCAP];
    __shared__ int cnt_gt, cnt_eq;
    int be = blockIdx.x;
    int t  = threadIdx.x;
    const unsigned* row = comb + (size_t)be * NN;
    if (t == 0) { sh_prefix = 0u; sh_r = KK; cnt_gt = 0; cnt_eq = 0; }
#pragma unroll
    for (int pass = 0; pass < 4; ++pass) {
        int shift = 24 - 8 * pass;
        unsigned hm = (pass == 0) ? 0u : (0xFFFFFFFFu << (shift + 8));
        hist[t] = 0;
        __syncthreads();
        unsigned pf = sh_prefix;
        for (int n = t; n < NN; n += 256) {
            unsigned u = row[n];
            if ((u & hm) == (pf & hm)) atomicAdd(&hist[(u >> shift) & 255], 1u);
        }
        __syncthreads();
        if (t == 0) {
            unsigned cum = 0, r = (unsigned)sh_r;
            for (int bin = 255; bin >= 0; --bin) {
                unsigned c = hist[bin];
                if (cum + c >= r) { sh_prefix |= (unsigned)bin << shift; sh_r = (int)(r - cum); break; }
                cum += c;
            }
        }
        __syncthreads();
    }
    unsigned T = sh_prefix;
    int r = sh_r;
    for (int n = t; n < NN; n += 256) {
        unsigned u = row[n];
        if (u > T) {
            int p = atomicAdd(&cnt_gt, 1);
            sel[be * KK + p] = n;
        } else if (u == T) {
            int p = atomicAdd(&cnt_eq, 1);
            if (p < EQCAP) eqi[p] = n;
        }
    }
    __syncthreads();
    int ne = cnt_eq < EQCAP ? cnt_eq : EQCAP;
    if (t < ne) {
        int mine = eqi[t], rk = 0;
        for (int j = 0; j < ne; ++j) rk += (eqi[j] < mine);
        if (rk < r) sel[be * KK + cnt_gt + rk] = mine;
    }
}

// ---------------- K5: scatter ones into H (B, N, Ne) ----------------
__global__ __launch_bounds__(256) void k_scatter(const int* __restrict__ sel,
                                                 float* __restrict__ H) {
    int gid = blockIdx.x * 256 + threadIdx.x;   // [0, B*NE*KK)
    int b = gid >> 13;                          // NE*KK = 8192
    int e = (gid >> 6) & 127;
    int n = sel[gid];
    H[((size_t)b * NN + n) * NE + e] = 1.0f;
}

extern "C" void kernel_launch(void* const* d_in, const int* in_sizes, int n_in,
                              void* d_out, int out_size, void* d_ws, size_t ws_size,
                              hipStream_t stream) {
    const float* nf   = (const float*)d_in[0];   // (B, N, C) f32
    const float* ct   = (const float*)d_in[1];   // (1, 1, C) f32
    const float* temp = (const float*)d_in[2];   // (1,) f32
    float* out = (float*)d_out;                  // (B, N, Ne) f32 — also (B,Ne,N) u32-key scratch

    unsigned* keys   = (unsigned*)d_ws;                    // B*N
    float* invn      = (float*)(keys + BB * NN);           // B*N
    int*   cidx      = (int*)(invn + BB * NN);             // B*NE
    float* meta      = (float*)(cidx + BB * NE);           // B*NE*4
    float* centers_n = meta + BB * NE * 4;                 // B*NE*C
    int*   sel       = (int*)(centers_n + BB * NE * CC);   // B*NE*KK

    k_scores <<<BB * NN / 4, 256, 0, stream>>>(nf, ct, keys, invn);
    k_top128 <<<BB, 1024, 0, stream>>>(keys, cidx);
    k_centers<<<BB * NE, 128, 0, stream>>>(nf, invn, cidx, centers_n, meta);
    k_gemm   <<<dim3(NN / 64, BB), 256, 0, stream>>>(nf, centers_n, invn, meta, temp, (unsigned*)out);
    k_top64  <<<BB * NE, 256, 0, stream>>>((const unsigned*)out, sel);
    hipMemsetAsync(d_out, 0, (size_t)BB * NN * NE * sizeof(float), stream);
    k_scatter<<<BB * NE * KK / 256, 256, 0, stream>>>(sel, out);
}

// Round 3
// 259.296 us; speedup vs baseline: 2.6763x; 1.5973x over previous
//
#include <hip/hip_runtime.h>
#include <math.h>

#define BB 4
#define NN 16384
#define CC 384
#define NE 128
#define KK 64
#define EQCAP 256
#define ROWP 130

typedef unsigned short ushort_t;
typedef __attribute__((ext_vector_type(8))) short bf16x8;
typedef __attribute__((ext_vector_type(4))) float f32x4;
#define MFMA(a, b, c) __builtin_amdgcn_mfma_f32_16x16x32_bf16(a, b, c, 0, 0, 0)

// Monotone map: larger float -> larger u32
__device__ inline unsigned fkey(float f) {
    unsigned b = __float_as_uint(f);
    return (b & 0x80000000u) ? ~b : (b | 0x80000000u);
}
__device__ inline ushort_t bf16rne(float f) {
    unsigned u = __float_as_uint(f);
    unsigned r = u + 0x7FFFu + ((u >> 16) & 1u);
    return (ushort_t)(r >> 16);
}
__device__ inline float bf16tof(ushort_t h) {
    return __uint_as_float(((unsigned)h) << 16);
}
#define CVT2(fa, fb, outh, outl) { \
    ushort_t ha = bf16rne(fa), hb = bf16rne(fb); \
    float la = (fa) - bf16tof(ha), lb = (fb) - bf16tof(hb); \
    outh = (unsigned)ha | ((unsigned)hb << 16); \
    outl = (unsigned)bf16rne(la) | ((unsigned)bf16rne(lb) << 16); }

// Parallel bin select over 256-bin LDS histogram (call with all 1024 threads).
// Finds bin s.t. (#elems in bins > bin) < r <= (#elems in bins >= bin).
__device__ inline void bin_select(unsigned* hist, int t, int* wsum,
                                  int* sh_bin, int* sh_r, int r) {
    int lane = t & 63, wid = t >> 6;
    int c = (t < 256) ? (int)hist[t] : 0;
    int x = c;
#pragma unroll
    for (int off = 1; off < 64; off <<= 1) {
        int v = __shfl_down(x, off, 64);
        if (lane + off < 64) x += v;         // inclusive suffix within wave
    }
    if (lane == 0 && wid < 4) wsum[wid] = x;
    __syncthreads();
    if (t < 256) {
        int add = 0;
        for (int w2 = wid + 1; w2 < 4; ++w2) add += wsum[w2];
        int S_incl = x + add;
        int S_excl = S_incl - c;
        if (S_excl < r && S_incl >= r) { *sh_bin = t; *sh_r = r - S_excl; }
    }
    __syncthreads();
}

// ---------------- K1: per-row sumsq + class-token dot -> u32 ranking key ----------------
__global__ __launch_bounds__(256) void k_scores(const float* __restrict__ nf,
                                                const float* __restrict__ ct,
                                                unsigned* __restrict__ keys,
                                                float* __restrict__ invn) {
    int wave = threadIdx.x >> 6;
    int lane = threadIdx.x & 63;
    int row  = blockIdx.x * 4 + wave;
    const float* x = nf + (size_t)row * CC;
    float4 a  = ((const float4*)x)[lane];
    float2 c2 = ((const float2*)(x + 256))[lane];
    float4 ta = ((const float4*)ct)[lane];
    float2 tc = ((const float2*)(ct + 256))[lane];
    float ss = a.x*a.x + a.y*a.y + a.z*a.z + a.w*a.w + c2.x*c2.x + c2.y*c2.y;
    float dt = ta.x*a.x + ta.y*a.y + ta.z*a.z + ta.w*a.w + tc.x*c2.x + tc.y*c2.y;
#pragma unroll
    for (int off = 32; off; off >>= 1) {
        ss += __shfl_xor(ss, off, 64);
        dt += __shfl_xor(dt, off, 64);
    }
    if (lane == 0) {
        float inv = 1.0f / fmaxf(sqrtf(ss), 1e-12f);
        invn[row] = inv;
        keys[row] = fkey(dt * inv);
    }
}

// ---------------- K2: top-128 centers per batch via radix select (order matters) ----------------
__global__ __launch_bounds__(1024) void k_top128(const unsigned* __restrict__ keys,
                                                 int* __restrict__ cidx) {
    __shared__ unsigned hist[256];
    __shared__ int wsum[4];
    __shared__ int sh_bin, sh_r;
    __shared__ unsigned cu[NE];
    __shared__ int cil[NE];
    __shared__ int eqi[EQCAP];
    __shared__ int cnt_gt, cnt_eq;
    int b = blockIdx.x;
    int t = threadIdx.x;
    const uint4* rowv = (const uint4*)(keys + b * NN);
    if (t == 0) { cnt_gt = 0; cnt_eq = 0; }
    unsigned prefix = 0;
    int r = NE;
#pragma unroll
    for (int pass = 0; pass < 4; ++pass) {
        int shift = 24 - 8 * pass;
        unsigned hm = (pass == 0) ? 0u : (0xFFFFFFFFu << (shift + 8));
        if (t < 256) hist[t] = 0;
        __syncthreads();
#pragma unroll
        for (int i = 0; i < 4; ++i) {
            uint4 u = rowv[t + 1024 * i];
            if ((u.x & hm) == (prefix & hm)) atomicAdd(&hist[(u.x >> shift) & 255], 1u);
            if ((u.y & hm) == (prefix & hm)) atomicAdd(&hist[(u.y >> shift) & 255], 1u);
            if ((u.z & hm) == (prefix & hm)) atomicAdd(&hist[(u.z >> shift) & 255], 1u);
            if ((u.w & hm) == (prefix & hm)) atomicAdd(&hist[(u.w >> shift) & 255], 1u);
        }
        __syncthreads();
        bin_select(hist, t, wsum, &sh_bin, &sh_r, r);
        prefix |= ((unsigned)sh_bin) << shift;
        r = sh_r;
        __syncthreads();
    }
    unsigned T = prefix;
#pragma unroll
    for (int i = 0; i < 4; ++i) {
        uint4 u = rowv[t + 1024 * i];
        int nb = 4 * (t + 1024 * i);
        unsigned vv[4] = {u.x, u.y, u.z, u.w};
#pragma unroll
        for (int cmp = 0; cmp < 4; ++cmp) {
            if (vv[cmp] > T) {
                int p = atomicAdd(&cnt_gt, 1);
                cu[p] = vv[cmp]; cil[p] = nb + cmp;
            } else if (vv[cmp] == T) {
                int p = atomicAdd(&cnt_eq, 1);
                if (p < EQCAP) eqi[p] = nb + cmp;
            }
        }
    }
    __syncthreads();
    int ne = cnt_eq < EQCAP ? cnt_eq : EQCAP;
    if (t < ne) {
        int mine = eqi[t], rk = 0;
        for (int j = 0; j < ne; ++j) rk += (eqi[j] < mine);
        if (rk < r) { int p = cnt_gt + rk; cu[p] = T; cil[p] = mine; }
    }
    __syncthreads();
    if (t < NE) {
        unsigned mu = cu[t]; int mi = cil[t], rk = 0;
#pragma unroll 4
        for (int j = 0; j < NE; ++j) {
            unsigned ou = cu[j]; int oi = cil[j];
            rk += (ou > mu) || (ou == mu && oi < mi);
        }
        cidx[b * NE + rk] = mi;
    }
}

// ---------------- K2b: gather centers -> bf16 hi/lo split + spatial meta ----------------
__global__ __launch_bounds__(128) void k_centers(const float* __restrict__ nf,
                                                 const float* __restrict__ invn,
                                                 const int* __restrict__ cidx,
                                                 ushort_t* __restrict__ Ahi,
                                                 ushort_t* __restrict__ Alo,
                                                 float* __restrict__ meta) {
    int be = blockIdx.x;
    int b  = be >> 7;
    int ci = cidx[be];
    float inv = invn[b * NN + ci];
    const float* src = nf + ((size_t)b * NN + ci) * CC;
    for (int c = threadIdx.x; c < CC; c += 128) {
        float f = src[c] * inv;
        ushort_t h = bf16rne(f);
        Ahi[(size_t)be * CC + c] = h;
        Alo[(size_t)be * CC + c] = bf16rne(f - bf16tof(h));
    }
    if (threadIdx.x == 0) {
        float zc = (float)(ci >> 10) * 2.0f;
        float yc = (float)((ci >> 5) & 31);
        float xc = (float)(ci & 31);
        float mz = fmaxf(zc * zc, (30.f - zc) * (30.f - zc));
        float my = fmaxf(yc * yc, (31.f - yc) * (31.f - yc));
        float mx = fmaxf(xc * xc, (31.f - xc) * (31.f - xc));
        float md = sqrtf(mz + my + mx);
        meta[be * 4 + 0] = zc;
        meta[be * 4 + 1] = yc;
        meta[be * 4 + 2] = xc;
        meta[be * 4 + 3] = 1.0f / (md + 1e-8f);
    }
}

// ---------------- K3: bf16-split MFMA GEMM (128 edges x 128 nodes/block) ----------------
// acc = Ahi*Bhi + Ahi*Blo + Alo*Bhi  (3x mfma_f32_16x16x32_bf16), fp32 accumulate.
__global__ __launch_bounds__(256) void k_gemm(const float* __restrict__ nf,
                                              const ushort_t* __restrict__ Ahi,
                                              const ushort_t* __restrict__ Alo,
                                              const float* __restrict__ invn,
                                              const float* __restrict__ meta,
                                              const float* __restrict__ temp,
                                              unsigned* __restrict__ outk) {
    __shared__ ushort_t Ah[4][ROWP][8], Al_[4][ROWP][8], Bh[4][ROWP][8], Bl[4][ROWP][8];
    __shared__ float ms[NE * 4];
    __shared__ float invs_s[128];
    int b  = blockIdx.y;
    int n0 = blockIdx.x * 128;
    int t  = threadIdx.x;
    int w  = t >> 6, lane = t & 63;
    int quad = lane >> 4, mrow = lane & 15;
    int m0 = (w & 1) * 64, nw0 = (w >> 1) * 64;
    for (int i = t; i < NE * 4; i += 256) ms[i] = meta[b * NE * 4 + i];
    if (t < 128) invs_s[t] = invn[b * NN + n0 + t];
    f32x4 acc[4][4];
#pragma unroll
    for (int i = 0; i < 4; ++i)
#pragma unroll
        for (int j = 0; j < 4; ++j) acc[i][j] = (f32x4)0.f;
    const ushort_t* Abh = Ahi + (size_t)b * NE * CC;
    const ushort_t* Abl = Alo + (size_t)b * NE * CC;
    const float* Bb = nf + ((size_t)b * NN + n0) * CC;
    for (int kt = 0; kt < CC; kt += 32) {
        __syncthreads();
#pragma unroll
        for (int i = 0; i < 2; ++i) {            // A: 128 e x 4 k8-chunks
            int c = t + 256 * i;
            int e = c >> 2, k8 = c & 3;
            int off = e * CC + kt + k8 * 8;
            *(uint4*)&Ah[k8][e][0]  = *(const uint4*)(Abh + off);
            *(uint4*)&Al_[k8][e][0] = *(const uint4*)(Abl + off);
        }
#pragma unroll
        for (int i = 0; i < 2; ++i) {            // B: 128 n x 4 k8-chunks, fp32 -> hi/lo
            int c = t + 256 * i;
            int n = c >> 2, k8 = c & 3;
            const float* src = Bb + (size_t)n * CC + kt + k8 * 8;
            float4 fa = ((const float4*)src)[0];
            float4 fb = ((const float4*)src)[1];
            uint4 ph, pl;
            CVT2(fa.x, fa.y, ph.x, pl.x);
            CVT2(fa.z, fa.w, ph.y, pl.y);
            CVT2(fb.x, fb.y, ph.z, pl.z);
            CVT2(fb.z, fb.w, ph.w, pl.w);
            *(uint4*)&Bh[k8][n][0] = ph;
            *(uint4*)&Bl[k8][n][0] = pl;
        }
        __syncthreads();
        bf16x8 afh[4], afl[4], bfh[4], bfl[4];
#pragma unroll
        for (int i = 0; i < 4; ++i) {
            afh[i] = *(const bf16x8*)&Ah[quad][m0 + i * 16 + mrow][0];
            afl[i] = *(const bf16x8*)&Al_[quad][m0 + i * 16 + mrow][0];
            bfh[i] = *(const bf16x8*)&Bh[quad][nw0 + i * 16 + mrow][0];
            bfl[i] = *(const bf16x8*)&Bl[quad][nw0 + i * 16 + mrow][0];
        }
#pragma unroll
        for (int i = 0; i < 4; ++i)
#pragma unroll
            for (int j = 0; j < 4; ++j) {
                acc[i][j] = MFMA(afh[i], bfh[j], acc[i][j]);
                acc[i][j] = MFMA(afh[i], bfl[j], acc[i][j]);
                acc[i][j] = MFMA(afl[i], bfh[j], acc[i][j]);
            }
    }
    float scale = 0.9f / temp[0];
#pragma unroll
    for (int j = 0; j < 4; ++j) {
        int nloc = nw0 + j * 16 + (lane & 15);
        int n = n0 + nloc;
        float invnn = invs_s[nloc];
        float zf = (float)(n >> 10) * 2.0f;
        float yf = (float)((n >> 5) & 31);
        float xf = (float)(n & 31);
#pragma unroll
        for (int i = 0; i < 4; ++i) {
#pragma unroll
            for (int r = 0; r < 4; ++r) {
                int e = m0 + i * 16 + quad * 4 + r;
                float zc = ms[e * 4 + 0], yc = ms[e * 4 + 1], xc = ms[e * 4 + 2], ivd = ms[e * 4 + 3];
                float dz = zf - zc, dy = yf - yc, dx = xf - xc;
                float dist = sqrtf(dz * dz + dy * dy + dx * dx);
                float v = scale * invnn * acc[i][j][r] + 0.1f * (1.0f - dist * ivd);
                outk[((size_t)(b * NE + e)) * NN + n] = fkey(v);
            }
        }
    }
}

// ---------------- K4: top-64 per hyperedge via radix select (set only) ----------------
__global__ __launch_bounds__(1024) void k_top64(const unsigned* __restrict__ comb,
                                                int* __restrict__ sel) {
    __shared__ unsigned hist[256];
    __shared__ int wsum[4];
    __shared__ int sh_bin, sh_r;
    __shared__ int eqi[EQCAP];
    __shared__ int cnt_gt, cnt_eq;
    int be = blockIdx.x;
    int t  = threadIdx.x;
    const uint4* rowv = (const uint4*)(comb + (size_t)be * NN);
    if (t == 0) { cnt_gt = 0; cnt_eq = 0; }
    unsigned prefix = 0;
    int r = KK;
#pragma unroll
    for (int pass = 0; pass < 4; ++pass) {
        int shift = 24 - 8 * pass;
        unsigned hm = (pass == 0) ? 0u : (0xFFFFFFFFu << (shift + 8));
        if (t < 256) hist[t] = 0;
        __syncthreads();
#pragma unroll
        for (int i = 0; i < 4; ++i) {
            uint4 u = rowv[t + 1024 * i];
            if ((u.x & hm) == (prefix & hm)) atomicAdd(&hist[(u.x >> shift) & 255], 1u);
            if ((u.y & hm) == (prefix & hm)) atomicAdd(&hist[(u.y >> shift) & 255], 1u);
            if ((u.z & hm) == (prefix & hm)) atomicAdd(&hist[(u.z >> shift) & 255], 1u);
            if ((u.w & hm) == (prefix & hm)) atomicAdd(&hist[(u.w >> shift) & 255], 1u);
        }
        __syncthreads();
        bin_select(hist, t, wsum, &sh_bin, &sh_r, r);
        prefix |= ((unsigned)sh_bin) << shift;
        r = sh_r;
        __syncthreads();
    }
    unsigned T = prefix;
#pragma unroll
    for (int i = 0; i < 4; ++i) {
        uint4 u = rowv[t + 1024 * i];
        int nb = 4 * (t + 1024 * i);
        unsigned vv[4] = {u.x, u.y, u.z, u.w};
#pragma unroll
        for (int cmp = 0; cmp < 4; ++cmp) {
            if (vv[cmp] > T) {
                int p = atomicAdd(&cnt_gt, 1);
                sel[be * KK + p] = nb + cmp;
            } else if (vv[cmp] == T) {
                int p = atomicAdd(&cnt_eq, 1);
                if (p < EQCAP) eqi[p] = nb + cmp;
            }
        }
    }
    __syncthreads();
    int ne = cnt_eq < EQCAP ? cnt_eq : EQCAP;
    if (t < ne) {
        int mine = eqi[t], rk = 0;
        for (int j = 0; j < ne; ++j) rk += (eqi[j] < mine);
        if (rk < r) sel[be * KK + cnt_gt + rk] = mine;
    }
}

// ---------------- K5: scatter ones into H (B, N, Ne) ----------------
__global__ __launch_bounds__(256) void k_scatter(const int* __restrict__ sel,
                                                 float* __restrict__ H) {
    int gid = blockIdx.x * 256 + threadIdx.x;
    int b = gid >> 13;
    int e = (gid >> 6) & 127;
    int n = sel[gid];
    H[((size_t)b * NN + n) * NE + e] = 1.0f;
}

extern "C" void kernel_launch(void* const* d_in, const int* in_sizes, int n_in,
                              void* d_out, int out_size, void* d_ws, size_t ws_size,
                              hipStream_t stream) {
    const float* nf   = (const float*)d_in[0];
    const float* ct   = (const float*)d_in[1];
    const float* temp = (const float*)d_in[2];
    float* out = (float*)d_out;                  // (B,N,Ne) f32 — also (B,Ne,N) u32-key scratch

    unsigned* keys = (unsigned*)d_ws;                      // B*N u32
    float* invn    = (float*)(keys + BB * NN);             // B*N f32
    float* meta    = invn + BB * NN;                       // B*NE*4 f32
    ushort_t* Ahi  = (ushort_t*)(meta + BB * NE * 4);      // B*NE*C bf16
    ushort_t* Alo  = Ahi + (size_t)BB * NE * CC;           // B*NE*C bf16
    int* cidx      = (int*)(Alo + (size_t)BB * NE * CC);   // B*NE
    int* sel       = cidx + BB * NE;                       // B*NE*KK

    k_scores <<<BB * NN / 4, 256, 0, stream>>>(nf, ct, keys, invn);
    k_top128 <<<BB, 1024, 0, stream>>>(keys, cidx);
    k_centers<<<BB * NE, 128, 0, stream>>>(nf, invn, cidx, Ahi, Alo, meta);
    k_gemm   <<<dim3(NN / 128, BB), 256, 0, stream>>>(nf, Ahi, Alo, invn, meta, temp, (unsigned*)out);
    k_top64  <<<BB * NE, 1024, 0, stream>>>((const unsigned*)out, sel);
    hipMemsetAsync(d_out, 0, (size_t)BB * NN * NE * sizeof(float), stream);
    k_scatter<<<BB * NE * KK / 256, 256, 0, stream>>>(sel, out);
}